// Round 7
// baseline (195.225 us; speedup 1.0000x reference)
//
#include <hip/hip_runtime.h>
#include <hip/hip_bf16.h>

// Problem constants
// B=32, N=96, NODE_DIM=2048, COND_DIM=1024, E=128
// NODES = 32*96 = 3072, EDGES = 32*96*95 = 291840
// out: [291840, 128] (f32, per round-1 WRITE_SIZE evidence)
//
// Round 7 = round-6 with the nontemporal-store compile fix (ext_vector_type
// pointers instead of HIP_vector_type). k_edge: no Wl1 LDS staging (global
// reads, L1-resident 32KB), nontemporal output stores. Base otherwise
// byte-identical to round 4 (proven 161us).

#define WS_FLAG      0
#define WS_BIAS      256        // 4 bias vectors f32[128], each at 512B stride
#define WS_WN_NODE   4096       // bf16 [128][2048]
#define WS_WN_JOINT  528384     // bf16 [128][256]
#define WS_WN_Q      593920     // bf16 [128][1024]
#define WS_WN_LIN    856064     // bf16 [128][256]
#define WS_H         921600     // bf16 [3072][128]
#define WS_P         1708032    // f32 [3072][128]
#define WS_Q         3280896    // f32 [3072][128]
#define WS_QC        4853760    // f32 [32][128]

typedef __bf16 bf16x8 __attribute__((ext_vector_type(8)));
typedef float  f32x4  __attribute__((ext_vector_type(4)));
typedef ushort us4    __attribute__((ext_vector_type(4)));

union BF8 { bf16x8 v; ushort u[8]; uint4 q; };

__device__ __forceinline__ float b2f(ushort u){ union{uint i; float f;} c; c.i=(uint)u<<16; return c.f; }
__device__ __forceinline__ ushort f2b(float f){ union{float f; uint i;} c; c.f=f; uint i=c.i; return (ushort)((i + 0x7FFFu + ((i>>16)&1u))>>16); }
// dual-dtype scalar load: bf=1 -> buffer holds bf16, bf=0 -> f32
__device__ __forceinline__ float getv(const void* p, int i, int bf){
  return bf ? b2f(((const ushort*)p)[i]) : ((const float*)p)[i];
}

// ---------------------------------------------------------------- detect dtype
__global__ void k_detect(const void* g_node_g, int* flag){
  if (threadIdx.x==0){
    const ushort* p = (const ushort*)g_node_g;
    int ok = 1;
    for (int i=0;i<64;i++){ float v = b2f(p[i]); if (!(v>0.35f && v<1.75f)) ok=0; }
    *flag = ok;
  }
}

// ---------------------------------------------------------------- weight norm
__global__ __launch_bounds__(256) void k_norm(
    const void* v0,const void* g0,const void* b0,
    const void* v1,const void* g1,const void* b1,
    const void* v2,const void* g2,const void* b2_,
    const void* v3,const void* g3,const void* b3,
    char* ws){
  const int bf = *(const int*)(ws + WS_FLAG);
  int m = blockIdx.x >> 7;       // which matrix
  int r = blockIdx.x & 127;      // row
  const void* V; const void* G; const void* Bv; int C; ushort* dst;
  if      (m==0){ V=v0; G=g0; Bv=b0;  C=2048; dst=(ushort*)(ws+WS_WN_NODE); }
  else if (m==1){ V=v1; G=g1; Bv=b1;  C=256;  dst=(ushort*)(ws+WS_WN_JOINT); }
  else if (m==2){ V=v2; G=g2; Bv=b2_; C=1024; dst=(ushort*)(ws+WS_WN_Q); }
  else          { V=v3; G=g3; Bv=b3;  C=256;  dst=(ushort*)(ws+WS_WN_LIN); }
  int t = threadIdx.x;
  float ss = 0.f;
  for (int c=t;c<C;c+=256){ float x = getv(V, r*C+c, bf); ss += x*x; }
  for (int d=32;d>0;d>>=1) ss += __shfl_down(ss, d, 64);
  __shared__ float part[4];
  if ((t&63)==0) part[t>>6] = ss;
  __syncthreads();
  float scale = getv(G, r, bf) * rsqrtf(part[0]+part[1]+part[2]+part[3]);
  for (int c=t;c<C;c+=256) dst[r*C+c] = f2b(getv(V, r*C+c, bf)*scale);
  if (r==0 && t<128) ((float*)(ws + WS_BIAS + m*512))[t] = getv(Bv, t, bf);
}

// ---------------------------------------------------------------- h = relu(x @ Wn^T + b)
// M=3072, K=2048, N=128. wave = (mtile of 16 rows) x (half of N).
__global__ __launch_bounds__(256) void k_h(const void* xg, const char* ws, ushort* h){
  const int bf = *(const int*)(ws + WS_FLAG);
  const ushort* W = (const ushort*)(ws + WS_WN_NODE);
  const float* bias = (const float*)(ws + WS_BIAS + 0);
  int wid = threadIdx.x >> 6, lane = threadIdx.x & 63;
  int gw = blockIdx.x*4 + wid;        // 384 waves
  int mtile = gw >> 1, nh = gw & 1;
  int row = lane & 15, g = lane >> 4;
  size_t xr = (size_t)(mtile*16 + row);
  f32x4 acc[4] = {};
  for (int kk=0; kk<64; kk++){
    int off = kk*32 + g*8;
    BF8 a;
    if (bf) {
      a.q = *(const uint4*)((const ushort*)xg + xr*2048 + off);
    } else {
      const float* xp = (const float*)xg + xr*2048 + off;
      float4 x0 = ((const float4*)xp)[0], x1 = ((const float4*)xp)[1];
      a.u[0]=f2b(x0.x); a.u[1]=f2b(x0.y); a.u[2]=f2b(x0.z); a.u[3]=f2b(x0.w);
      a.u[4]=f2b(x1.x); a.u[5]=f2b(x1.y); a.u[6]=f2b(x1.z); a.u[7]=f2b(x1.w);
    }
    #pragma unroll
    for (int nt=0; nt<4; nt++){
      int wr = (nh*4+nt)*16 + row;
      BF8 bv; bv.q = *(const uint4*)(W + (size_t)wr*2048 + off);
      acc[nt] = __builtin_amdgcn_mfma_f32_16x16x32_bf16(a.v, bv.v, acc[nt], 0,0,0);
    }
  }
  #pragma unroll
  for (int nt=0; nt<4; nt++){
    #pragma unroll
    for (int r2=0; r2<4; r2++){
      int hr = mtile*16 + g*4 + r2;            // D row = (lane>>4)*4 + reg  [m89]
      int hc = (nh*4+nt)*16 + row;             // D col = lane&15
      float v = acc[nt][r2] + bias[hc];
      h[(size_t)hr*128 + hc] = f2b(v>0.f? v:0.f);
    }
  }
}

// ---------------------------------------------------------------- P = h@Wj1^T, Q = h@Wj2^T  (f32 out, no relu/bias yet)
__global__ __launch_bounds__(256) void k_pq(const char* ws, float* Pp, float* Qp){
  const ushort* h  = (const ushort*)(ws + WS_H);
  const ushort* Wj = (const ushort*)(ws + WS_WN_JOINT);
  int wid = threadIdx.x>>6, lane = threadIdx.x&63;
  int mtile = blockIdx.x*4 + wid;   // 192
  int row = lane&15, g = lane>>4;
  f32x4 acc[16] = {};
  #pragma unroll
  for (int kk=0; kk<4; kk++){
    int off = kk*32 + g*8;
    BF8 a; a.q = *(const uint4*)(h + (size_t)(mtile*16+row)*128 + off);
    #pragma unroll
    for (int vt=0; vt<16; vt++){
      int wr = (vt&7)*16 + row;
      int woff = (vt>>3)*128 + off;            // vt<8 -> Wj1 (cols 0..127), vt>=8 -> Wj2
      BF8 bv; bv.q = *(const uint4*)(Wj + (size_t)wr*256 + woff);
      acc[vt] = __builtin_amdgcn_mfma_f32_16x16x32_bf16(a.v, bv.v, acc[vt], 0,0,0);
    }
  }
  #pragma unroll
  for (int vt=0; vt<16; vt++){
    float* dst = (vt<8)? Pp : Qp;
    #pragma unroll
    for (int r2=0;r2<4;r2++){
      int mr = mtile*16 + g*4 + r2;
      int col = (vt&7)*16 + row;
      dst[(size_t)mr*128 + col] = acc[vt][r2];
    }
  }
}

// ---------------------------------------------------------------- qc[b] = Wl2 @ relu(Wq@cond_b + qb) + lb
__global__ __launch_bounds__(128) void k_qc(const void* cond, const char* ws, float* qc){
  const int bf = *(const int*)(ws + WS_FLAG);
  const ushort* Wq = (const ushort*)(ws + WS_WN_Q);
  const ushort* Wl = (const ushort*)(ws + WS_WN_LIN);
  const float* qb = (const float*)(ws + WS_BIAS + 2*512);
  const float* lb = (const float*)(ws + WS_BIAS + 3*512);
  __shared__ float cs[1024];
  __shared__ float qs[128];
  int b = blockIdx.x, t = threadIdx.x;
  for (int ii=0; ii<8; ii++) cs[t*8+ii] = getv(cond, b*1024 + t*8+ii, bf);
  __syncthreads();
  float s = 0.f;
  for (int c8=0; c8<128; c8++){
    BF8 w; w.q = *(const uint4*)(Wq + (size_t)t*1024 + c8*8);
    #pragma unroll
    for (int ii=0;ii<8;ii++) s += b2f(w.u[ii]) * cs[c8*8+ii];
  }
  s += qb[t];
  qs[t] = s>0.f? s:0.f;
  __syncthreads();
  float s2 = 0.f;
  for (int c8=0; c8<16; c8++){
    BF8 w; w.q = *(const uint4*)(Wl + (size_t)t*256 + 128 + c8*8);
    #pragma unroll
    for (int ii=0;ii<8;ii++) s2 += b2f(w.u[ii]) * qs[c8*8+ii];
  }
  qc[b*128 + t] = s2 + lb[t];
}

// ---------------------------------------------------------------- main edge kernel
// out_e = relu( Wl1 @ relu(P_i + Q_j + bj) + qc[b] )
// block = 4 waves x 32 edges = 128 edges. Wl1 read directly from global
// (L1-resident 32KB; value-identical to round-4's staged path); only the 512B
// bias vector in LDS. Nontemporal output stores via ext_vector pointers.
// mfma(A=Wl1_frag, B=joint_frag): D reg-dim = output column -> float4 stores.
__global__ __launch_bounds__(256) void k_edge(const int* eidx, const char* ws, void* out){
  const int bf = *(const int*)(ws + WS_FLAG);
  const float* Pp = (const float*)(ws + WS_P);
  const float* Qp = (const float*)(ws + WS_Q);
  const float* qc = (const float*)(ws + WS_QC);
  const ushort* Wl = (const ushort*)(ws + WS_WN_LIN);
  const float* bj = (const float*)(ws + WS_BIAS + 1*512);
  __shared__ float bjl[128];
  int t = threadIdx.x;
  if (t<128) bjl[t] = bj[t];
  __syncthreads();

  int wid = t>>6, lane = t&63;
  int row = lane&15, g = lane>>4;
  int wbase = blockIdx.x*128 + wid*32;

  // gather joint = relu(P_i + Q_j + bj), pack bf16 (B-operand fragments)
  int b2m[2];
  BF8 af[2][4];
  #pragma unroll
  for (int m=0;m<2;m++){
    int e = wbase + m*16 + row;
    int idx = eidx[e];
    int b = idx/9216; int rem = idx - b*9216;
    int i2 = rem/96;  int j2 = rem - i2*96;
    b2m[m] = b;
    const float* Pr = Pp + (size_t)(b*96+i2)*128;
    const float* Qr = Qp + (size_t)(b*96+j2)*128;
    #pragma unroll
    for (int kk=0;kk<4;kk++){
      int off = kk*32 + g*8;
      float4 p0 = *(const float4*)(Pr+off); float4 p1 = *(const float4*)(Pr+off+4);
      float4 q0 = *(const float4*)(Qr+off); float4 q1 = *(const float4*)(Qr+off+4);
      BF8 a;
      float v0 = p0.x+q0.x+bjl[off+0]; a.u[0]=f2b(v0>0?v0:0);
      float v1 = p0.y+q0.y+bjl[off+1]; a.u[1]=f2b(v1>0?v1:0);
      float v2 = p0.z+q0.z+bjl[off+2]; a.u[2]=f2b(v2>0?v2:0);
      float v3 = p0.w+q0.w+bjl[off+3]; a.u[3]=f2b(v3>0?v3:0);
      float v4 = p1.x+q1.x+bjl[off+4]; a.u[4]=f2b(v4>0?v4:0);
      float v5 = p1.y+q1.y+bjl[off+5]; a.u[5]=f2b(v5>0?v5:0);
      float v6 = p1.z+q1.z+bjl[off+6]; a.u[6]=f2b(v6>0?v6:0);
      float v7 = p1.w+q1.w+bjl[off+7]; a.u[7]=f2b(v7>0?v7:0);
      af[m][kk].q = a.q;
    }
  }

  f32x4 acc[2][8] = {};
  #pragma unroll
  for (int kk=0;kk<4;kk++){
    #pragma unroll
    for (int nt=0;nt<8;nt++){
      int wr = nt*16 + row;
      BF8 aw; aw.q = *(const uint4*)(Wl + (size_t)wr*256 + kk*32 + g*8);
      acc[0][nt] = __builtin_amdgcn_mfma_f32_16x16x32_bf16(aw.v, af[0][kk].v, acc[0][nt], 0,0,0);
      acc[1][nt] = __builtin_amdgcn_mfma_f32_16x16x32_bf16(aw.v, af[1][kk].v, acc[1][nt], 0,0,0);
    }
  }

  // acc[m][nt][r2] = out[edge = wbase+m*16+row][col = nt*16+g*4+r2]
  #pragma unroll
  for (int m=0;m<2;m++){
    const float* qcb = qc + b2m[m]*128;
    size_t obase = (size_t)(wbase + m*16 + row)*128;
    #pragma unroll
    for (int nt=0;nt<8;nt++){
      int col0 = nt*16 + g*4;
      float4 q4 = *(const float4*)(qcb + col0);
      float v0 = acc[m][nt][0] + q4.x; v0 = v0>0.f? v0:0.f;
      float v1 = acc[m][nt][1] + q4.y; v1 = v1>0.f? v1:0.f;
      float v2 = acc[m][nt][2] + q4.z; v2 = v2>0.f? v2:0.f;
      float v3 = acc[m][nt][3] + q4.w; v3 = v3>0.f? v3:0.f;
      if (bf){
        us4 o = { f2b(v0), f2b(v1), f2b(v2), f2b(v3) };
        __builtin_nontemporal_store(o, (us4*)((ushort*)out + obase + col0));
      } else {
        f32x4 o = { v0, v1, v2, v3 };
        __builtin_nontemporal_store(o, (f32x4*)((float*)out + obase + col0));
      }
    }
  }
}

extern "C" void kernel_launch(void* const* d_in, const int* in_sizes, int n_in,
                              void* d_out, int out_size, void* d_ws, size_t ws_size,
                              hipStream_t stream) {
  (void)in_sizes; (void)n_in; (void)out_size; (void)ws_size;
  char* ws = (char*)d_ws;
  k_detect<<<1, 64, 0, stream>>>(d_in[4], (int*)(ws + WS_FLAG));
  k_norm<<<512, 256, 0, stream>>>(d_in[3], d_in[4], d_in[5],
                                  d_in[6], d_in[7], d_in[8],
                                  d_in[9], d_in[10], d_in[11],
                                  d_in[12], d_in[13], d_in[14], ws);
  k_h<<<96, 256, 0, stream>>>(d_in[0], ws, (ushort*)(ws + WS_H));
  k_pq<<<48, 256, 0, stream>>>(ws, (float*)(ws + WS_P), (float*)(ws + WS_Q));
  k_qc<<<32, 128, 0, stream>>>(d_in[1], ws, (float*)(ws + WS_QC));
  k_edge<<<2280, 256, 0, stream>>>((const int*)d_in[2], ws, d_out);
}

// Round 8
// 165.316 us; speedup vs baseline: 1.1809x; 1.1809x over previous
//
#include <hip/hip_runtime.h>
#include <hip/hip_bf16.h>

// Problem constants
// B=32, N=96, NODE_DIM=2048, COND_DIM=1024, E=128
// NODES = 32*96 = 3072, EDGES = 32*96*95 = 291840
// out: [291840, 128] (f32, per WRITE_SIZE evidence)
//
// Round 8 = round-4 core (proven 161us; nt-stores + global-Wl REVERTED after
// round-7 regression: WRITE_SIZE +31% from partial-line nt flushes) with:
//   (a) k_edge: 2 tiles per block (grid 1140) -- identical body x2, staging
//       amortized, compiler free to overlap tile-1 gathers with tile-0 MFMA.
//   (b) k_h: 384 x 64-thread blocks (all CUs engaged; was 96 blocks/96 CUs),
//       #pragma unroll 2 on K-loop. Body bit-exact.
//   (c) k_pq: 192 x 64-thread blocks (was 48 blocks/48 CUs). Body bit-exact.

#define WS_FLAG      0
#define WS_BIAS      256        // 4 bias vectors f32[128], each at 512B stride
#define WS_WN_NODE   4096       // bf16 [128][2048]
#define WS_WN_JOINT  528384     // bf16 [128][256]
#define WS_WN_Q      593920     // bf16 [128][1024]
#define WS_WN_LIN    856064     // bf16 [128][256]
#define WS_H         921600     // bf16 [3072][128]
#define WS_P         1708032    // f32 [3072][128]
#define WS_Q         3280896    // f32 [3072][128]
#define WS_QC        4853760    // f32 [32][128]

typedef __bf16 bf16x8 __attribute__((ext_vector_type(8)));
typedef float  f32x4  __attribute__((ext_vector_type(4)));

union BF8 { bf16x8 v; ushort u[8]; uint4 q; };

__device__ __forceinline__ float b2f(ushort u){ union{uint i; float f;} c; c.i=(uint)u<<16; return c.f; }
__device__ __forceinline__ ushort f2b(float f){ union{float f; uint i;} c; c.f=f; uint i=c.i; return (ushort)((i + 0x7FFFu + ((i>>16)&1u))>>16); }
// dual-dtype scalar load: bf=1 -> buffer holds bf16, bf=0 -> f32
__device__ __forceinline__ float getv(const void* p, int i, int bf){
  return bf ? b2f(((const ushort*)p)[i]) : ((const float*)p)[i];
}

// ---------------------------------------------------------------- detect dtype
__global__ void k_detect(const void* g_node_g, int* flag){
  if (threadIdx.x==0){
    const ushort* p = (const ushort*)g_node_g;
    int ok = 1;
    for (int i=0;i<64;i++){ float v = b2f(p[i]); if (!(v>0.35f && v<1.75f)) ok=0; }
    *flag = ok;
  }
}

// ---------------------------------------------------------------- weight norm
__global__ __launch_bounds__(256) void k_norm(
    const void* v0,const void* g0,const void* b0,
    const void* v1,const void* g1,const void* b1,
    const void* v2,const void* g2,const void* b2_,
    const void* v3,const void* g3,const void* b3,
    char* ws){
  const int bf = *(const int*)(ws + WS_FLAG);
  int m = blockIdx.x >> 7;       // which matrix
  int r = blockIdx.x & 127;      // row
  const void* V; const void* G; const void* Bv; int C; ushort* dst;
  if      (m==0){ V=v0; G=g0; Bv=b0;  C=2048; dst=(ushort*)(ws+WS_WN_NODE); }
  else if (m==1){ V=v1; G=g1; Bv=b1;  C=256;  dst=(ushort*)(ws+WS_WN_JOINT); }
  else if (m==2){ V=v2; G=g2; Bv=b2_; C=1024; dst=(ushort*)(ws+WS_WN_Q); }
  else          { V=v3; G=g3; Bv=b3;  C=256;  dst=(ushort*)(ws+WS_WN_LIN); }
  int t = threadIdx.x;
  float ss = 0.f;
  for (int c=t;c<C;c+=256){ float x = getv(V, r*C+c, bf); ss += x*x; }
  for (int d=32;d>0;d>>=1) ss += __shfl_down(ss, d, 64);
  __shared__ float part[4];
  if ((t&63)==0) part[t>>6] = ss;
  __syncthreads();
  float scale = getv(G, r, bf) * rsqrtf(part[0]+part[1]+part[2]+part[3]);
  for (int c=t;c<C;c+=256) dst[r*C+c] = f2b(getv(V, r*C+c, bf)*scale);
  if (r==0 && t<128) ((float*)(ws + WS_BIAS + m*512))[t] = getv(Bv, t, bf);
}

// ---------------------------------------------------------------- h = relu(x @ Wn^T + b)
// M=3072, K=2048, N=128. ROUND-8: one wave per block (grid 384 = mtile x nh),
// body bit-exact vs round 4; K-loop unroll 2 for load overlap.
__global__ __launch_bounds__(64) void k_h(const void* xg, const char* ws, ushort* h){
  const int bf = *(const int*)(ws + WS_FLAG);
  const ushort* W = (const ushort*)(ws + WS_WN_NODE);
  const float* bias = (const float*)(ws + WS_BIAS + 0);
  int lane = threadIdx.x & 63;
  int gw = blockIdx.x;                // 384 waves
  int mtile = gw >> 1, nh = gw & 1;
  int row = lane & 15, g = lane >> 4;
  size_t xr = (size_t)(mtile*16 + row);
  f32x4 acc[4] = {};
  #pragma unroll 2
  for (int kk=0; kk<64; kk++){
    int off = kk*32 + g*8;
    BF8 a;
    if (bf) {
      a.q = *(const uint4*)((const ushort*)xg + xr*2048 + off);
    } else {
      const float* xp = (const float*)xg + xr*2048 + off;
      float4 x0 = ((const float4*)xp)[0], x1 = ((const float4*)xp)[1];
      a.u[0]=f2b(x0.x); a.u[1]=f2b(x0.y); a.u[2]=f2b(x0.z); a.u[3]=f2b(x0.w);
      a.u[4]=f2b(x1.x); a.u[5]=f2b(x1.y); a.u[6]=f2b(x1.z); a.u[7]=f2b(x1.w);
    }
    #pragma unroll
    for (int nt=0; nt<4; nt++){
      int wr = (nh*4+nt)*16 + row;
      BF8 bv; bv.q = *(const uint4*)(W + (size_t)wr*2048 + off);
      acc[nt] = __builtin_amdgcn_mfma_f32_16x16x32_bf16(a.v, bv.v, acc[nt], 0,0,0);
    }
  }
  #pragma unroll
  for (int nt=0; nt<4; nt++){
    #pragma unroll
    for (int r2=0; r2<4; r2++){
      int hr = mtile*16 + g*4 + r2;            // D row = (lane>>4)*4 + reg  [m89]
      int hc = (nh*4+nt)*16 + row;             // D col = lane&15
      float v = acc[nt][r2] + bias[hc];
      h[(size_t)hr*128 + hc] = f2b(v>0.f? v:0.f);
    }
  }
}

// ---------------------------------------------------------------- P = h@Wj1^T, Q = h@Wj2^T  (f32 out, no relu/bias yet)
// ROUND-8: one wave per block (grid 192); body bit-exact vs round 4.
__global__ __launch_bounds__(64) void k_pq(const char* ws, float* Pp, float* Qp){
  const ushort* h  = (const ushort*)(ws + WS_H);
  const ushort* Wj = (const ushort*)(ws + WS_WN_JOINT);
  int lane = threadIdx.x&63;
  int mtile = blockIdx.x;   // 192
  int row = lane&15, g = lane>>4;
  f32x4 acc[16] = {};
  #pragma unroll
  for (int kk=0; kk<4; kk++){
    int off = kk*32 + g*8;
    BF8 a; a.q = *(const uint4*)(h + (size_t)(mtile*16+row)*128 + off);
    #pragma unroll
    for (int vt=0; vt<16; vt++){
      int wr = (vt&7)*16 + row;
      int woff = (vt>>3)*128 + off;            // vt<8 -> Wj1 (cols 0..127), vt>=8 -> Wj2
      BF8 bv; bv.q = *(const uint4*)(Wj + (size_t)wr*256 + woff);
      acc[vt] = __builtin_amdgcn_mfma_f32_16x16x32_bf16(a.v, bv.v, acc[vt], 0,0,0);
    }
  }
  #pragma unroll
  for (int vt=0; vt<16; vt++){
    float* dst = (vt<8)? Pp : Qp;
    #pragma unroll
    for (int r2=0;r2<4;r2++){
      int mr = mtile*16 + g*4 + r2;
      int col = (vt&7)*16 + row;
      dst[(size_t)mr*128 + col] = acc[vt][r2];
    }
  }
}

// ---------------------------------------------------------------- qc[b] = Wl2 @ relu(Wq@cond_b + qb) + lb
__global__ __launch_bounds__(128) void k_qc(const void* cond, const char* ws, float* qc){
  const int bf = *(const int*)(ws + WS_FLAG);
  const ushort* Wq = (const ushort*)(ws + WS_WN_Q);
  const ushort* Wl = (const ushort*)(ws + WS_WN_LIN);
  const float* qb = (const float*)(ws + WS_BIAS + 2*512);
  const float* lb = (const float*)(ws + WS_BIAS + 3*512);
  __shared__ float cs[1024];
  __shared__ float qs[128];
  int b = blockIdx.x, t = threadIdx.x;
  for (int ii=0; ii<8; ii++) cs[t*8+ii] = getv(cond, b*1024 + t*8+ii, bf);
  __syncthreads();
  float s = 0.f;
  for (int c8=0; c8<128; c8++){
    BF8 w; w.q = *(const uint4*)(Wq + (size_t)t*1024 + c8*8);
    #pragma unroll
    for (int ii=0;ii<8;ii++) s += b2f(w.u[ii]) * cs[c8*8+ii];
  }
  s += qb[t];
  qs[t] = s>0.f? s:0.f;
  __syncthreads();
  float s2 = 0.f;
  for (int c8=0; c8<16; c8++){
    BF8 w; w.q = *(const uint4*)(Wl + (size_t)t*256 + 128 + c8*8);
    #pragma unroll
    for (int ii=0;ii<8;ii++) s2 += b2f(w.u[ii]) * qs[c8*8+ii];
  }
  qc[b*128 + t] = s2 + lb[t];
}

// ---------------------------------------------------------------- main edge kernel
// out_e = relu( Wl1 @ relu(P_i + Q_j + bj) + qc[b] )
// ROUND-8: round-4 body (LDS-staged Wl1, XOR swizzle, float4 stores) run for
// TWO 128-edge tiles per block (grid 1140); staging amortized across tiles.
__global__ __launch_bounds__(256) void k_edge(const int* eidx, const char* ws, void* out){
  const int bf = *(const int*)(ws + WS_FLAG);
  const float* Pp = (const float*)(ws + WS_P);
  const float* Qp = (const float*)(ws + WS_Q);
  const float* qc = (const float*)(ws + WS_QC);
  const ushort* Wl = (const ushort*)(ws + WS_WN_LIN);
  const float* bj = (const float*)(ws + WS_BIAS + 1*512);
  __shared__ __align__(16) char wlds[32768 + 512];
  float* bjl = (float*)(wlds + 32768);
  int t = threadIdx.x;
  #pragma unroll
  for (int it=0; it<8; it++){
    int cid = t + it*256;             // 128 rows x 16 chunks of 16B
    int r = cid >> 4, cb = cid & 15;
    uint4 src = *(const uint4*)(Wl + (size_t)r*256 + cb*8);   // Wl1 = cols 0..127
    *(uint4*)(wlds + r*256 + ((cb*16) ^ ((r&7)<<4))) = src;
  }
  if (t<128) bjl[t] = bj[t];
  __syncthreads();

  int wid = t>>6, lane = t&63;
  int row = lane&15, g = lane>>4;

  #pragma unroll
  for (int tile=0; tile<2; tile++){
    int wbase = (blockIdx.x*2 + tile)*128 + wid*32;

    // gather joint = relu(P_i + Q_j + bj), pack bf16 (B-operand fragments)
    int b2m[2];
    BF8 af[2][4];
    #pragma unroll
    for (int m=0;m<2;m++){
      int e = wbase + m*16 + row;
      int idx = eidx[e];
      int b = idx/9216; int rem = idx - b*9216;
      int i2 = rem/96;  int j2 = rem - i2*96;
      b2m[m] = b;
      const float* Pr = Pp + (size_t)(b*96+i2)*128;
      const float* Qr = Qp + (size_t)(b*96+j2)*128;
      #pragma unroll
      for (int kk=0;kk<4;kk++){
        int off = kk*32 + g*8;
        float4 p0 = *(const float4*)(Pr+off); float4 p1 = *(const float4*)(Pr+off+4);
        float4 q0 = *(const float4*)(Qr+off); float4 q1 = *(const float4*)(Qr+off+4);
        BF8 a;
        float v0 = p0.x+q0.x+bjl[off+0]; a.u[0]=f2b(v0>0?v0:0);
        float v1 = p0.y+q0.y+bjl[off+1]; a.u[1]=f2b(v1>0?v1:0);
        float v2 = p0.z+q0.z+bjl[off+2]; a.u[2]=f2b(v2>0?v2:0);
        float v3 = p0.w+q0.w+bjl[off+3]; a.u[3]=f2b(v3>0?v3:0);
        float v4 = p1.x+q1.x+bjl[off+4]; a.u[4]=f2b(v4>0?v4:0);
        float v5 = p1.y+q1.y+bjl[off+5]; a.u[5]=f2b(v5>0?v5:0);
        float v6 = p1.z+q1.z+bjl[off+6]; a.u[6]=f2b(v6>0?v6:0);
        float v7 = p1.w+q1.w+bjl[off+7]; a.u[7]=f2b(v7>0?v7:0);
        af[m][kk].q = a.q;
      }
    }

    f32x4 acc[2][8] = {};
    #pragma unroll
    for (int kk=0;kk<4;kk++){
      #pragma unroll
      for (int nt=0;nt<8;nt++){
        int wr = nt*16 + row;
        BF8 aw; aw.q = *(const uint4*)(wlds + wr*256 + ((kk*64 + g*16) ^ ((wr&7)<<4)));
        acc[0][nt] = __builtin_amdgcn_mfma_f32_16x16x32_bf16(aw.v, af[0][kk].v, acc[0][nt], 0,0,0);
        acc[1][nt] = __builtin_amdgcn_mfma_f32_16x16x32_bf16(aw.v, af[1][kk].v, acc[1][nt], 0,0,0);
      }
    }

    // acc[m][nt][r2] = out[edge = wbase+m*16+row][col = nt*16+g*4+r2]
    #pragma unroll
    for (int m=0;m<2;m++){
      const float* qcb = qc + b2m[m]*128;
      size_t obase = (size_t)(wbase + m*16 + row)*128;
      #pragma unroll
      for (int nt=0;nt<8;nt++){
        int col0 = nt*16 + g*4;
        float4 q4 = *(const float4*)(qcb + col0);
        float v0 = acc[m][nt][0] + q4.x; v0 = v0>0.f? v0:0.f;
        float v1 = acc[m][nt][1] + q4.y; v1 = v1>0.f? v1:0.f;
        float v2 = acc[m][nt][2] + q4.z; v2 = v2>0.f? v2:0.f;
        float v3 = acc[m][nt][3] + q4.w; v3 = v3>0.f? v3:0.f;
        if (bf){
          union { ushort u[4]; ushort4 s; } o;
          o.u[0]=f2b(v0); o.u[1]=f2b(v1); o.u[2]=f2b(v2); o.u[3]=f2b(v3);
          *(ushort4*)((ushort*)out + obase + col0) = o.s;
        } else {
          float4 o; o.x=v0; o.y=v1; o.z=v2; o.w=v3;
          *(float4*)((float*)out + obase + col0) = o;
        }
      }
    }
  }
}

extern "C" void kernel_launch(void* const* d_in, const int* in_sizes, int n_in,
                              void* d_out, int out_size, void* d_ws, size_t ws_size,
                              hipStream_t stream) {
  (void)in_sizes; (void)n_in; (void)out_size; (void)ws_size;
  char* ws = (char*)d_ws;
  k_detect<<<1, 64, 0, stream>>>(d_in[4], (int*)(ws + WS_FLAG));
  k_norm<<<512, 256, 0, stream>>>(d_in[3], d_in[4], d_in[5],
                                  d_in[6], d_in[7], d_in[8],
                                  d_in[9], d_in[10], d_in[11],
                                  d_in[12], d_in[13], d_in[14], ws);
  k_h<<<384, 64, 0, stream>>>(d_in[0], ws, (ushort*)(ws + WS_H));
  k_pq<<<192, 64, 0, stream>>>(ws, (float*)(ws + WS_P), (float*)(ws + WS_Q));
  k_qc<<<32, 128, 0, stream>>>(d_in[1], ws, (float*)(ws + WS_QC));
  k_edge<<<1140, 256, 0, stream>>>((const int*)d_in[2], ws, d_out);
}

// Round 9
// 149.424 us; speedup vs baseline: 1.3065x; 1.1064x over previous
//
#include <hip/hip_runtime.h>
#include <hip/hip_bf16.h>

// Problem constants
// B=32, N=96, NODE_DIM=2048, COND_DIM=1024, E=128
// NODES = 32*96 = 3072, EDGES = 32*96*95 = 291840
// out: [291840, 128] (f32, per WRITE_SIZE evidence)
//
// Round 9 = round-8 base with k_edge back to 1 tile/block (2-tile regressed:
// serial per-block latency doubled) plus three latency-chain levers:
//   (a) k_edge: explicit per-m gather hoist (16 float4 into regs before pack)
//   (b) k_edge: bias via 8 hoisted global float4 (bit-exact values) instead of
//       LDS -> LDS exactly 32768 B -> 5 blocks/CU (was 4); pack loses 64
//       ds_read_b32
//   (c) k_detect launch removed -- detect_bf ballot inlined per kernel
//       (exonerated by rounds 2/3: weights were correct with this code)

#define WS_BIAS      256        // 4 bias vectors f32[128], each at 512B stride
#define WS_WN_NODE   4096       // bf16 [128][2048]
#define WS_WN_JOINT  528384     // bf16 [128][256]
#define WS_WN_Q      593920     // bf16 [128][1024]
#define WS_WN_LIN    856064     // bf16 [128][256]
#define WS_H         921600     // bf16 [3072][128]
#define WS_P         1708032    // f32 [3072][128]
#define WS_Q         3280896    // f32 [3072][128]
#define WS_QC        4853760    // f32 [32][128]

typedef __bf16 bf16x8 __attribute__((ext_vector_type(8)));
typedef float  f32x4  __attribute__((ext_vector_type(4)));

union BF8 { bf16x8 v; ushort u[8]; uint4 q; };

__device__ __forceinline__ float b2f(ushort u){ union{uint i; float f;} c; c.i=(uint)u<<16; return c.f; }
__device__ __forceinline__ ushort f2b(float f){ union{float f; uint i;} c; c.f=f; uint i=c.i; return (ushort)((i + 0x7FFFu + ((i>>16)&1u))>>16); }
// dual-dtype scalar load: bf=1 -> buffer holds bf16, bf=0 -> f32
__device__ __forceinline__ float getv(const void* p, int i, int bf){
  return bf ? b2f(((const ushort*)p)[i]) : ((const float*)p)[i];
}

// dtype probe: node_g ~ U(0.5,1.5). bf16 view of f32 puts mantissa garbage in
// even slots -> out-of-range values -> bf=0. (Proven in rounds 2/3: weight
// pipeline was correct with this exact probe.)
__device__ __forceinline__ int detect_bf(const void* g_node_g){
  const ushort* p = (const ushort*)g_node_g;
  float v = b2f(p[threadIdx.x & 63]);
  unsigned long long m = __ballot(v > 0.35f && v < 1.75f);
  return m == ~0ull;
}

// ---------------------------------------------------------------- weight norm
__global__ __launch_bounds__(256) void k_norm(
    const void* v0,const void* g0,const void* b0,
    const void* v1,const void* g1,const void* b1,
    const void* v2,const void* g2,const void* b2_,
    const void* v3,const void* g3,const void* b3,
    const void* gq, char* ws){
  const int bf = detect_bf(gq);
  int m = blockIdx.x >> 7;       // which matrix
  int r = blockIdx.x & 127;      // row
  const void* V; const void* G; const void* Bv; int C; ushort* dst;
  if      (m==0){ V=v0; G=g0; Bv=b0;  C=2048; dst=(ushort*)(ws+WS_WN_NODE); }
  else if (m==1){ V=v1; G=g1; Bv=b1;  C=256;  dst=(ushort*)(ws+WS_WN_JOINT); }
  else if (m==2){ V=v2; G=g2; Bv=b2_; C=1024; dst=(ushort*)(ws+WS_WN_Q); }
  else          { V=v3; G=g3; Bv=b3;  C=256;  dst=(ushort*)(ws+WS_WN_LIN); }
  int t = threadIdx.x;
  float ss = 0.f;
  for (int c=t;c<C;c+=256){ float x = getv(V, r*C+c, bf); ss += x*x; }
  for (int d=32;d>0;d>>=1) ss += __shfl_down(ss, d, 64);
  __shared__ float part[4];
  if ((t&63)==0) part[t>>6] = ss;
  __syncthreads();
  float scale = getv(G, r, bf) * rsqrtf(part[0]+part[1]+part[2]+part[3]);
  for (int c=t;c<C;c+=256) dst[r*C+c] = f2b(getv(V, r*C+c, bf)*scale);
  if (r==0 && t<128) ((float*)(ws + WS_BIAS + m*512))[t] = getv(Bv, t, bf);
}

// ---------------------------------------------------------------- h = relu(x @ Wn^T + b)
// M=3072, K=2048, N=128. One wave per block (grid 384 = mtile x nh); body
// bit-exact vs round 4; K-loop unroll 2 for load overlap.
__global__ __launch_bounds__(64) void k_h(const void* xg, const void* gq,
                                          const char* ws, ushort* h){
  const int bf = detect_bf(gq);
  const ushort* W = (const ushort*)(ws + WS_WN_NODE);
  const float* bias = (const float*)(ws + WS_BIAS + 0);
  int lane = threadIdx.x & 63;
  int gw = blockIdx.x;                // 384 waves
  int mtile = gw >> 1, nh = gw & 1;
  int row = lane & 15, g = lane >> 4;
  size_t xr = (size_t)(mtile*16 + row);
  f32x4 acc[4] = {};
  #pragma unroll 2
  for (int kk=0; kk<64; kk++){
    int off = kk*32 + g*8;
    BF8 a;
    if (bf) {
      a.q = *(const uint4*)((const ushort*)xg + xr*2048 + off);
    } else {
      const float* xp = (const float*)xg + xr*2048 + off;
      float4 x0 = ((const float4*)xp)[0], x1 = ((const float4*)xp)[1];
      a.u[0]=f2b(x0.x); a.u[1]=f2b(x0.y); a.u[2]=f2b(x0.z); a.u[3]=f2b(x0.w);
      a.u[4]=f2b(x1.x); a.u[5]=f2b(x1.y); a.u[6]=f2b(x1.z); a.u[7]=f2b(x1.w);
    }
    #pragma unroll
    for (int nt=0; nt<4; nt++){
      int wr = (nh*4+nt)*16 + row;
      BF8 bv; bv.q = *(const uint4*)(W + (size_t)wr*2048 + off);
      acc[nt] = __builtin_amdgcn_mfma_f32_16x16x32_bf16(a.v, bv.v, acc[nt], 0,0,0);
    }
  }
  #pragma unroll
  for (int nt=0; nt<4; nt++){
    #pragma unroll
    for (int r2=0; r2<4; r2++){
      int hr = mtile*16 + g*4 + r2;            // D row = (lane>>4)*4 + reg  [m89]
      int hc = (nh*4+nt)*16 + row;             // D col = lane&15
      float v = acc[nt][r2] + bias[hc];
      h[(size_t)hr*128 + hc] = f2b(v>0.f? v:0.f);
    }
  }
}

// ---------------------------------------------------------------- P = h@Wj1^T, Q = h@Wj2^T  (f32 out, no relu/bias yet)
// One wave per block (grid 192); body bit-exact vs round 4.
__global__ __launch_bounds__(64) void k_pq(const char* ws, float* Pp, float* Qp){
  const ushort* h  = (const ushort*)(ws + WS_H);
  const ushort* Wj = (const ushort*)(ws + WS_WN_JOINT);
  int lane = threadIdx.x&63;
  int mtile = blockIdx.x;   // 192
  int row = lane&15, g = lane>>4;
  f32x4 acc[16] = {};
  #pragma unroll
  for (int kk=0; kk<4; kk++){
    int off = kk*32 + g*8;
    BF8 a; a.q = *(const uint4*)(h + (size_t)(mtile*16+row)*128 + off);
    #pragma unroll
    for (int vt=0; vt<16; vt++){
      int wr = (vt&7)*16 + row;
      int woff = (vt>>3)*128 + off;            // vt<8 -> Wj1 (cols 0..127), vt>=8 -> Wj2
      BF8 bv; bv.q = *(const uint4*)(Wj + (size_t)wr*256 + woff);
      acc[vt] = __builtin_amdgcn_mfma_f32_16x16x32_bf16(a.v, bv.v, acc[vt], 0,0,0);
    }
  }
  #pragma unroll
  for (int vt=0; vt<16; vt++){
    float* dst = (vt<8)? Pp : Qp;
    #pragma unroll
    for (int r2=0;r2<4;r2++){
      int mr = mtile*16 + g*4 + r2;
      int col = (vt&7)*16 + row;
      dst[(size_t)mr*128 + col] = acc[vt][r2];
    }
  }
}

// ---------------------------------------------------------------- qc[b] = Wl2 @ relu(Wq@cond_b + qb) + lb
__global__ __launch_bounds__(128) void k_qc(const void* cond, const void* gq,
                                            const char* ws, float* qc){
  const int bf = detect_bf(gq);
  const ushort* Wq = (const ushort*)(ws + WS_WN_Q);
  const ushort* Wl = (const ushort*)(ws + WS_WN_LIN);
  const float* qb = (const float*)(ws + WS_BIAS + 2*512);
  const float* lb = (const float*)(ws + WS_BIAS + 3*512);
  __shared__ float cs[1024];
  __shared__ float qs[128];
  int b = blockIdx.x, t = threadIdx.x;
  for (int ii=0; ii<8; ii++) cs[t*8+ii] = getv(cond, b*1024 + t*8+ii, bf);
  __syncthreads();
  float s = 0.f;
  for (int c8=0; c8<128; c8++){
    BF8 w; w.q = *(const uint4*)(Wq + (size_t)t*1024 + c8*8);
    #pragma unroll
    for (int ii=0;ii<8;ii++) s += b2f(w.u[ii]) * cs[c8*8+ii];
  }
  s += qb[t];
  qs[t] = s>0.f? s:0.f;
  __syncthreads();
  float s2 = 0.f;
  for (int c8=0; c8<16; c8++){
    BF8 w; w.q = *(const uint4*)(Wl + (size_t)t*256 + 128 + c8*8);
    #pragma unroll
    for (int ii=0;ii<8;ii++) s2 += b2f(w.u[ii]) * qs[c8*8+ii];
  }
  qc[b*128 + t] = s2 + lb[t];
}

// ---------------------------------------------------------------- main edge kernel
// out_e = relu( Wl1 @ relu(P_i + Q_j + bj) + qc[b] )
// block = 4 waves x 32 edges = 128 edges, grid 2280 (1 tile/block).
// Wl1 LDS-staged with XOR swizzle (LDS exactly 32768 -> 5 blocks/CU).
// Bias via hoisted global float4 (bit-exact values, L1-broadcast).
// Per-m gather hoist: 16 float4 in regs before pack (explicit ILP).
// mfma(A=Wl1_frag, B=joint_frag): D reg-dim = output column -> float4 stores.
__global__ __launch_bounds__(256) void k_edge(const int* eidx, const void* gq,
                                              const char* ws, void* out){
  const int bf = detect_bf(gq);
  const float* Pp = (const float*)(ws + WS_P);
  const float* Qp = (const float*)(ws + WS_Q);
  const float* qc = (const float*)(ws + WS_QC);
  const ushort* Wl = (const ushort*)(ws + WS_WN_LIN);
  const float* bj = (const float*)(ws + WS_BIAS + 1*512);
  __shared__ __align__(16) char wlds[32768];
  int t = threadIdx.x;
  #pragma unroll
  for (int it=0; it<8; it++){
    int cid = t + it*256;             // 128 rows x 16 chunks of 16B
    int r = cid >> 4, cb = cid & 15;
    uint4 src = *(const uint4*)(Wl + (size_t)r*256 + cb*8);   // Wl1 = cols 0..127
    *(uint4*)(wlds + r*256 + ((cb*16) ^ ((r&7)<<4))) = src;
  }

  int wid = t>>6, lane = t&63;
  int row = lane&15, g = lane>>4;
  int wbase = blockIdx.x*128 + wid*32;

  // bias fragments for this lane's k-range (same for both m); L1-broadcast
  float4 c0[4], c1[4];
  #pragma unroll
  for (int kk=0;kk<4;kk++){
    int off = kk*32 + g*8;
    c0[kk] = *(const float4*)(bj + off);
    c1[kk] = *(const float4*)(bj + off + 4);
  }

  // edge decomposition for both m (independent loads, issue early)
  int b2m[2]; const float* Pr[2]; const float* Qr[2];
  #pragma unroll
  for (int m=0;m<2;m++){
    int e = wbase + m*16 + row;
    int idx = eidx[e];
    int b = idx/9216; int rem = idx - b*9216;
    int i2 = rem/96;  int j2 = rem - i2*96;
    b2m[m] = b;
    Pr[m] = Pp + (size_t)(b*96+i2)*128;
    Qr[m] = Qp + (size_t)(b*96+j2)*128;
  }
  __syncthreads();

  // gather joint = relu(P_i + Q_j + bj), pack bf16 (B-operand fragments)
  BF8 af[2][4];
  #pragma unroll
  for (int m=0;m<2;m++){
    float4 pv[8], qv[8];
    #pragma unroll
    for (int kk=0;kk<4;kk++){
      int off = kk*32 + g*8;
      pv[kk*2+0] = *(const float4*)(Pr[m]+off);
      pv[kk*2+1] = *(const float4*)(Pr[m]+off+4);
      qv[kk*2+0] = *(const float4*)(Qr[m]+off);
      qv[kk*2+1] = *(const float4*)(Qr[m]+off+4);
    }
    #pragma unroll
    for (int kk=0;kk<4;kk++){
      float4 p0 = pv[kk*2+0], p1 = pv[kk*2+1];
      float4 q0 = qv[kk*2+0], q1 = qv[kk*2+1];
      BF8 a;
      float v0 = p0.x+q0.x+c0[kk].x; a.u[0]=f2b(v0>0?v0:0);
      float v1 = p0.y+q0.y+c0[kk].y; a.u[1]=f2b(v1>0?v1:0);
      float v2 = p0.z+q0.z+c0[kk].z; a.u[2]=f2b(v2>0?v2:0);
      float v3 = p0.w+q0.w+c0[kk].w; a.u[3]=f2b(v3>0?v3:0);
      float v4 = p1.x+q1.x+c1[kk].x; a.u[4]=f2b(v4>0?v4:0);
      float v5 = p1.y+q1.y+c1[kk].y; a.u[5]=f2b(v5>0?v5:0);
      float v6 = p1.z+q1.z+c1[kk].z; a.u[6]=f2b(v6>0?v6:0);
      float v7 = p1.w+q1.w+c1[kk].w; a.u[7]=f2b(v7>0?v7:0);
      af[m][kk].q = a.q;
    }
  }

  f32x4 acc[2][8] = {};
  #pragma unroll
  for (int kk=0;kk<4;kk++){
    #pragma unroll
    for (int nt=0;nt<8;nt++){
      int wr = nt*16 + row;
      BF8 aw; aw.q = *(const uint4*)(wlds + wr*256 + ((kk*64 + g*16) ^ ((wr&7)<<4)));
      acc[0][nt] = __builtin_amdgcn_mfma_f32_16x16x32_bf16(aw.v, af[0][kk].v, acc[0][nt], 0,0,0);
      acc[1][nt] = __builtin_amdgcn_mfma_f32_16x16x32_bf16(aw.v, af[1][kk].v, acc[1][nt], 0,0,0);
    }
  }

  // acc[m][nt][r2] = out[edge = wbase+m*16+row][col = nt*16+g*4+r2]
  #pragma unroll
  for (int m=0;m<2;m++){
    const float* qcb = qc + b2m[m]*128;
    size_t obase = (size_t)(wbase + m*16 + row)*128;
    #pragma unroll
    for (int nt=0;nt<8;nt++){
      int col0 = nt*16 + g*4;
      float4 q4 = *(const float4*)(qcb + col0);
      float v0 = acc[m][nt][0] + q4.x; v0 = v0>0.f? v0:0.f;
      float v1 = acc[m][nt][1] + q4.y; v1 = v1>0.f? v1:0.f;
      float v2 = acc[m][nt][2] + q4.z; v2 = v2>0.f? v2:0.f;
      float v3 = acc[m][nt][3] + q4.w; v3 = v3>0.f? v3:0.f;
      if (bf){
        union { ushort u[4]; ushort4 s; } o;
        o.u[0]=f2b(v0); o.u[1]=f2b(v1); o.u[2]=f2b(v2); o.u[3]=f2b(v3);
        *(ushort4*)((ushort*)out + obase + col0) = o.s;
      } else {
        float4 o; o.x=v0; o.y=v1; o.z=v2; o.w=v3;
        *(float4*)((float*)out + obase + col0) = o;
      }
    }
  }
}

extern "C" void kernel_launch(void* const* d_in, const int* in_sizes, int n_in,
                              void* d_out, int out_size, void* d_ws, size_t ws_size,
                              hipStream_t stream) {
  (void)in_sizes; (void)n_in; (void)out_size; (void)ws_size;
  char* ws = (char*)d_ws;
  const void* gq = d_in[4];   // node_g, dtype probe
  k_norm<<<512, 256, 0, stream>>>(d_in[3], d_in[4], d_in[5],
                                  d_in[6], d_in[7], d_in[8],
                                  d_in[9], d_in[10], d_in[11],
                                  d_in[12], d_in[13], d_in[14], gq, ws);
  k_h<<<384, 64, 0, stream>>>(d_in[0], gq, ws, (ushort*)(ws + WS_H));
  k_pq<<<192, 64, 0, stream>>>(ws, (float*)(ws + WS_P), (float*)(ws + WS_Q));
  k_qc<<<32, 128, 0, stream>>>(d_in[1], gq, ws, (float*)(ws + WS_QC));
  k_edge<<<2280, 256, 0, stream>>>((const int*)d_in[2], gq, ws, d_out);
}